// Round 1
// baseline (1365.723 us; speedup 1.0000x reference)
//
#include <hip/hip_runtime.h>
#include <cstdint>
#include <cstddef>

// Problem constants (fixed by the reference's setup_inputs)
#define B_   2
#define S_   21760
#define M_   (B_ * S_)     // 43520 rows
#define D_   256
#define NH_  8
#define NL_  4
#define NP_  4
#define HD_  32
#define DFF_ 1024
#define EPS_ 1e-5f

// Level geometry (hardcoded: spatial_shapes = [(128,128),(64,64),(32,32),(16,16)])
__device__ __constant__ int c_lH[4] = {128, 64, 32, 16};
__device__ __constant__ int c_lW[4] = {128, 64, 32, 16};
__device__ __constant__ int c_lS[4] = {0, 16384, 20480, 21504};

// ---------------------------------------------------------------------------
// Generic fp32 GEMM: C[M,N] = act( (A [+ A2]) @ W + bias )
// BM=BN=64, BK=16, 256 threads, 4x4 microtile per thread.
// Requires M%64==0, N%64==0, K%16==0 (true for all calls here).
// ---------------------------------------------------------------------------
__global__ __launch_bounds__(256) void gemm64(
    const float* __restrict__ A, const float* __restrict__ A2,
    const float* __restrict__ W, const float* __restrict__ bias,
    float* __restrict__ C, int M, int N, int K, int do_relu)
{
    __shared__ __align__(16) float As[16][68];
    __shared__ __align__(16) float Bs[16][68];

    const int tid = threadIdx.x;
    const int tx = tid & 15, ty = tid >> 4;
    const int m0 = blockIdx.y << 6, n0 = blockIdx.x << 6;

    // A-tile loader: 64 rows x 16 cols, one float4 per thread
    const int la_row = tid >> 2, la_q = tid & 3;
    // B-tile loader: 16 rows x 64 cols, one float4 per thread
    const int lb_row = tid >> 4, lb_q = tid & 15;

    const float* Ap  = A + (size_t)(m0 + la_row) * K + la_q * 4;
    const float* A2p = A2 ? A2 + (size_t)(m0 + la_row) * K + la_q * 4 : nullptr;
    const float* Wp  = W + (size_t)lb_row * N + n0 + lb_q * 4;

    float acc[4][4] = {};

    for (int k0 = 0; k0 < K; k0 += 16) {
        float4 av = *(const float4*)(Ap + k0);
        if (A2p) {
            float4 a2 = *(const float4*)(A2p + k0);
            av.x += a2.x; av.y += a2.y; av.z += a2.z; av.w += a2.w;
        }
        float4 wv = *(const float4*)(Wp + (size_t)k0 * N);

        __syncthreads();
        As[la_q * 4 + 0][la_row] = av.x;
        As[la_q * 4 + 1][la_row] = av.y;
        As[la_q * 4 + 2][la_row] = av.z;
        As[la_q * 4 + 3][la_row] = av.w;
        *(float4*)&Bs[lb_row][lb_q * 4] = wv;
        __syncthreads();

        #pragma unroll
        for (int kk = 0; kk < 16; kk++) {
            float a[4], b[4];
            #pragma unroll
            for (int i = 0; i < 4; i++) a[i] = As[kk][ty * 4 + i];
            #pragma unroll
            for (int j = 0; j < 4; j++) b[j] = Bs[kk][tx * 4 + j];
            #pragma unroll
            for (int i = 0; i < 4; i++)
                #pragma unroll
                for (int j = 0; j < 4; j++)
                    acc[i][j] += a[i] * b[j];
        }
    }

    #pragma unroll
    for (int i = 0; i < 4; i++) {
        float4 o;
        o.x = acc[i][0] + bias[n0 + tx * 4 + 0];
        o.y = acc[i][1] + bias[n0 + tx * 4 + 1];
        o.z = acc[i][2] + bias[n0 + tx * 4 + 2];
        o.w = acc[i][3] + bias[n0 + tx * 4 + 3];
        if (do_relu) {
            o.x = fmaxf(o.x, 0.f); o.y = fmaxf(o.y, 0.f);
            o.z = fmaxf(o.z, 0.f); o.w = fmaxf(o.w, 0.f);
        }
        *(float4*)&C[(size_t)(m0 + ty * 4 + i) * N + n0 + tx * 4] = o;
    }
}

// ---------------------------------------------------------------------------
// In-place softmax over groups of 16 (one (q,h) per thread)
// ---------------------------------------------------------------------------
__global__ __launch_bounds__(256) void softmax16(float* __restrict__ aw, int total)
{
    int t = blockIdx.x * blockDim.x + threadIdx.x;
    if (t >= total) return;
    float* p = aw + (size_t)t * 16;
    float v[16];
    #pragma unroll
    for (int i = 0; i < 16; i++) v[i] = p[i];
    float m = v[0];
    #pragma unroll
    for (int i = 1; i < 16; i++) m = fmaxf(m, v[i]);
    float s = 0.f;
    #pragma unroll
    for (int i = 0; i < 16; i++) { v[i] = expf(v[i] - m); s += v[i]; }
    float inv = 1.f / s;
    #pragma unroll
    for (int i = 0; i < 16; i++) p[i] = v[i] * inv;
}

// ---------------------------------------------------------------------------
// Deformable attention sampling.
// Block = (32 channels, 8 heads) per query. out[bq, h*32+d].
// ---------------------------------------------------------------------------
__global__ __launch_bounds__(256) void sample_kernel(
    const float* __restrict__ value, const float* __restrict__ off,
    const float* __restrict__ aw, const float* __restrict__ refp,
    float* __restrict__ out)
{
    const int bq = blockIdx.x;            // 0..M_-1
    const int b  = bq / S_;
    const int d  = threadIdx.x;           // 0..31
    const int h  = threadIdx.y;           // 0..7

    const float* rp  = refp + (size_t)bq * (NL_ * 2);
    const float* ofq = off  + (size_t)bq * 256 + h * 32;   // (NH,NL,NP,2)
    const float* awq = aw   + (size_t)bq * 128 + h * 16;   // (NH,NL*NP)
    const float* vb  = value + ((size_t)b * S_) * D_ + h * HD_ + d;

    float acc = 0.f;

    #pragma unroll
    for (int l = 0; l < NL_; l++) {
        const int Hl = c_lH[l], Wl = c_lW[l], st = c_lS[l];
        const float fW = (float)Wl, fH = (float)Hl;
        const float rx = rp[l * 2 + 0], ry = rp[l * 2 + 1];
        #pragma unroll
        for (int p = 0; p < NP_; p++) {
            const int s = l * NP_ + p;
            const float a  = awq[s];
            const float ox = ofq[s * 2 + 0];
            const float oy = ofq[s * 2 + 1];
            // loc = ref + off/[w,h]; x = loc_x*W - 0.5, y = loc_y*H - 0.5
            const float x = (rx + ox / fW) * fW - 0.5f;
            const float y = (ry + oy / fH) * fH - 0.5f;
            const float fx0 = floorf(x), fy0 = floorf(y);
            const float dx = x - fx0, dy = y - fy0;
            const int x0 = (int)fx0, y0 = (int)fy0;
            const float w00 = (1.f - dx) * (1.f - dy);
            const float w10 = dx * (1.f - dy);
            const float w01 = (1.f - dx) * dy;
            const float w11 = dx * dy;

            float sv = 0.f;
            {   // (x0, y0)
                const bool ok = (x0 >= 0) & (x0 < Wl) & (y0 >= 0) & (y0 < Hl);
                const int xc = min(max(x0, 0), Wl - 1), yc = min(max(y0, 0), Hl - 1);
                const float val = vb[(size_t)(st + yc * Wl + xc) * D_];
                sv += ok ? w00 * val : 0.f;
            }
            {   // (x0+1, y0)
                const bool ok = (x0 + 1 >= 0) & (x0 + 1 < Wl) & (y0 >= 0) & (y0 < Hl);
                const int xc = min(max(x0 + 1, 0), Wl - 1), yc = min(max(y0, 0), Hl - 1);
                const float val = vb[(size_t)(st + yc * Wl + xc) * D_];
                sv += ok ? w10 * val : 0.f;
            }
            {   // (x0, y0+1)
                const bool ok = (x0 >= 0) & (x0 < Wl) & (y0 + 1 >= 0) & (y0 + 1 < Hl);
                const int xc = min(max(x0, 0), Wl - 1), yc = min(max(y0 + 1, 0), Hl - 1);
                const float val = vb[(size_t)(st + yc * Wl + xc) * D_];
                sv += ok ? w01 * val : 0.f;
            }
            {   // (x0+1, y0+1)
                const bool ok = (x0 + 1 >= 0) & (x0 + 1 < Wl) & (y0 + 1 >= 0) & (y0 + 1 < Hl);
                const int xc = min(max(x0 + 1, 0), Wl - 1), yc = min(max(y0 + 1, 0), Hl - 1);
                const float val = vb[(size_t)(st + yc * Wl + xc) * D_];
                sv += ok ? w11 * val : 0.f;
            }
            acc += a * sv;
        }
    }
    out[(size_t)bq * D_ + h * HD_ + d] = acc;
}

// ---------------------------------------------------------------------------
// Fused residual-add + LayerNorm over D=256. One block (256 threads) per row.
// out[row] = LN(a[row] + r[row]) * g + be
// ---------------------------------------------------------------------------
__global__ __launch_bounds__(256) void ln_fused(
    const float* __restrict__ a, const float* __restrict__ r,
    const float* __restrict__ g, const float* __restrict__ be,
    float* __restrict__ out)
{
    const int row = blockIdx.x;
    const int t = threadIdx.x;
    const size_t base = (size_t)row * D_ + t;

    float v = a[base] + r[base];

    __shared__ float red[4], red2[4];
    const int wid = t >> 6, lane = t & 63;

    float s = v;
    #pragma unroll
    for (int o = 32; o > 0; o >>= 1) s += __shfl_down(s, o);
    if (lane == 0) red[wid] = s;
    __syncthreads();
    const float mean = (red[0] + red[1] + red[2] + red[3]) * (1.f / 256.f);

    const float dv = v - mean;
    float s2 = dv * dv;
    #pragma unroll
    for (int o = 32; o > 0; o >>= 1) s2 += __shfl_down(s2, o);
    if (lane == 0) red2[wid] = s2;
    __syncthreads();
    const float var = (red2[0] + red2[1] + red2[2] + red2[3]) * (1.f / 256.f);

    out[base] = dv * rsqrtf(var + EPS_) * g[t] + be[t];
}

// ---------------------------------------------------------------------------
extern "C" void kernel_launch(void* const* d_in, const int* in_sizes, int n_in,
                              void* d_out, int out_size, void* d_ws, size_t ws_size,
                              hipStream_t stream)
{
    const float* src    = (const float*)d_in[0];
    const float* pos    = (const float*)d_in[1];
    const float* refp   = (const float*)d_in[2];
    // d_in[3] spatial_shapes, d_in[4] level_start_index: hardcoded
    const float* W_off  = (const float*)d_in[5];
    const float* b_off  = (const float*)d_in[6];
    const float* W_attn = (const float*)d_in[7];
    const float* b_attn = (const float*)d_in[8];
    const float* W_val  = (const float*)d_in[9];
    const float* b_val  = (const float*)d_in[10];
    const float* W_out  = (const float*)d_in[11];
    const float* b_out  = (const float*)d_in[12];
    const float* g1     = (const float*)d_in[13];
    const float* be1    = (const float*)d_in[14];
    const float* W_ff1  = (const float*)d_in[15];
    const float* b_ff1  = (const float*)d_in[16];
    const float* W_ff2  = (const float*)d_in[17];
    const float* b_ff2  = (const float*)d_in[18];
    const float* g2     = (const float*)d_in[19];
    const float* be2    = (const float*)d_in[20];
    float* out = (float*)d_out;

    const size_t szMD = (size_t)M_ * D_ * sizeof(float);      // 44.56 MB
    const size_t szAW = (size_t)M_ * 128 * sizeof(float);     // 22.28 MB

    char* ws = (char*)d_ws;
    float* value = (float*)(ws);
    float* offb  = (float*)(ws + szMD);
    float* awb   = (float*)(ws + 2 * szMD);
    float* samp  = (float*)(ws + 2 * szMD + szAW);
    float* hbuf  = (float*)(ws + 3 * szMD + szAW);
    // Reuse after lifetimes end:
    float* attn_out = offb;   // off dead after sampling
    float* xbuf     = value;  // value dead after sampling
    float* ffnbuf   = samp;   // samp dead after W_out GEMM

    // FFN hidden chunk sized from remaining workspace
    const size_t hoff = 3 * szMD + szAW;
    size_t avail = (ws_size > hoff) ? (ws_size - hoff) : 0;
    int chRows = (int)(avail / ((size_t)DFF_ * sizeof(float)));
    if (chRows > M_) chRows = M_;
    chRows &= ~63;
    if (chRows <= 0) chRows = 64;  // last resort; needs ~156MB+ of ws regardless

    // 1) value = src @ W_val + b_val
    gemm64<<<dim3(D_ / 64, M_ / 64), 256, 0, stream>>>(src, nullptr, W_val, b_val, value, M_, D_, D_, 0);
    // 2) off = (src+pos) @ W_off + b_off
    gemm64<<<dim3(256 / 64, M_ / 64), 256, 0, stream>>>(src, pos, W_off, b_off, offb, M_, 256, D_, 0);
    // 3) aw = (src+pos) @ W_attn + b_attn
    gemm64<<<dim3(128 / 64, M_ / 64), 256, 0, stream>>>(src, pos, W_attn, b_attn, awb, M_, 128, D_, 0);
    // 4) softmax over 16
    softmax16<<<(M_ * NH_ + 255) / 256, 256, 0, stream>>>(awb, M_ * NH_);
    // 5) deformable sampling
    sample_kernel<<<M_, dim3(32, 8), 0, stream>>>(value, offb, awb, refp, samp);
    // 6) attn_out = samp @ W_out + b_out
    gemm64<<<dim3(D_ / 64, M_ / 64), 256, 0, stream>>>(samp, nullptr, W_out, b_out, attn_out, M_, D_, D_, 0);
    // 7) x = LN(src + attn_out)
    ln_fused<<<M_, 256, 0, stream>>>(src, attn_out, g1, be1, xbuf);
    // 8) FFN (chunked over rows)
    for (int r = 0; r < M_; r += chRows) {
        int ch = M_ - r; if (ch > chRows) ch = chRows;
        gemm64<<<dim3(DFF_ / 64, ch / 64), 256, 0, stream>>>(
            xbuf + (size_t)r * D_, nullptr, W_ff1, b_ff1, hbuf, ch, DFF_, D_, 1);
        gemm64<<<dim3(D_ / 64, ch / 64), 256, 0, stream>>>(
            hbuf, nullptr, W_ff2, b_ff2, ffnbuf + (size_t)r * D_, ch, D_, DFF_, 0);
    }
    // 9) out = LN(x + ffn)
    ln_fused<<<M_, 256, 0, stream>>>(xbuf, ffnbuf, g2, be2, out);
}

// Round 2
// 365.451 us; speedup vs baseline: 3.7371x; 3.7371x over previous
//
#include <hip/hip_runtime.h>
#include <cstdint>
#include <cstddef>

#define B_   2
#define S_   21760
#define M_   (B_ * S_)     // 43520
#define D_   256
#define DFF_ 1024
#define EPS_ 1e-5f

typedef __attribute__((ext_vector_type(8))) short short8;
typedef __attribute__((ext_vector_type(4))) float f32x4;

__device__ __forceinline__ ushort f2bf(float f) {
    uint x = __float_as_uint(f);
    return (ushort)((x + 0x7fffu + ((x >> 16) & 1u)) >> 16);
}
__device__ __forceinline__ float bf2f(ushort u) {
    return __uint_as_float(((uint)u) << 16);
}

__device__ __constant__ int c_lH[4] = {128, 64, 32, 16};
__device__ __constant__ int c_lW[4] = {128, 64, 32, 16};
__device__ __constant__ int c_lS[4] = {0, 16384, 20480, 21504};

// ---------------------------------------------------------------------------
// Weight transpose+convert: WT[n][k] = bf16(W[k][n])
// ---------------------------------------------------------------------------
__global__ __launch_bounds__(256) void wconv(
    const float* __restrict__ W, ushort* __restrict__ WT, int K, int N)
{
    const int i = blockIdx.x * 256 + threadIdx.x;
    if (i >= K * N) return;
    const int n = i / K, k = i - n * K;
    WT[i] = f2bf(W[(size_t)k * N + n]);
}

// ---------------------------------------------------------------------------
// src_bf = bf16(src); q_bf = bf16(src + pos)
// ---------------------------------------------------------------------------
__global__ __launch_bounds__(256) void cvt_pair(
    const float* __restrict__ src, const float* __restrict__ pos,
    ushort* __restrict__ sb, ushort* __restrict__ qb)
{
    const size_t i = ((size_t)blockIdx.x * 256 + threadIdx.x) * 4;
    if (i >= (size_t)M_ * 256) return;
    const float4 s = *(const float4*)(src + i);
    const float4 p = *(const float4*)(pos + i);
    ushort4 so, qo;
    so.x = f2bf(s.x); so.y = f2bf(s.y); so.z = f2bf(s.z); so.w = f2bf(s.w);
    qo.x = f2bf(s.x + p.x); qo.y = f2bf(s.y + p.y);
    qo.z = f2bf(s.z + p.z); qo.w = f2bf(s.w + p.w);
    *(ushort4*)(sb + i) = so;
    *(ushort4*)(qb + i) = qo;
}

// ---------------------------------------------------------------------------
// bf16 MFMA GEMM: C[M,N] (bf16) = act(A[M,K](bf16) @ WT[N,K](bf16)^T + bias)
// 128x128 tile, BK=32, 4 waves (2x2), 4x4 16x16x32 fragments per wave.
// global_load_lds width-16 staging into linear LDS.
// ---------------------------------------------------------------------------
__global__ __launch_bounds__(256) void mgemm(
    const ushort* __restrict__ A, const ushort* __restrict__ WT,
    const float* __restrict__ bias, ushort* __restrict__ C,
    int M, int N, int K, int relu)
{
    __shared__ __align__(16) ushort Als[128 * 32];
    __shared__ __align__(16) ushort Bls[128 * 32];

    const int tid = threadIdx.x;
    const int wv = tid >> 6, ln = tid & 63;
    const int m0 = blockIdx.y << 7, n0 = blockIdx.x << 7;
    const int wm = wv >> 1, wn = wv & 1;

    const int lrow = ln >> 2, lcol = (ln & 3) * 8;

    f32x4 acc[4][4];
    const f32x4 zz = {0.f, 0.f, 0.f, 0.f};
    #pragma unroll
    for (int i = 0; i < 4; i++)
        #pragma unroll
        for (int j = 0; j < 4; j++) acc[i][j] = zz;

    for (int k0 = 0; k0 < K; k0 += 32) {
        __syncthreads();
        #pragma unroll
        for (int r = 0; r < 2; ++r) {
            const int c = r * 4 + wv;
            const ushort* ga = A + (size_t)(m0 + c * 16 + lrow) * K + k0 + lcol;
            __builtin_amdgcn_global_load_lds(
                (const __attribute__((address_space(1))) uint*)ga,
                (__attribute__((address_space(3))) uint*)(Als + c * 512), 16, 0, 0);
            const ushort* gb = WT + (size_t)(n0 + c * 16 + lrow) * K + k0 + lcol;
            __builtin_amdgcn_global_load_lds(
                (const __attribute__((address_space(1))) uint*)gb,
                (__attribute__((address_space(3))) uint*)(Bls + c * 512), 16, 0, 0);
        }
        __syncthreads();

        const int fr = ln & 15, kb = (ln >> 4) * 8;
        short8 af[4], bfr[4];
        #pragma unroll
        for (int i = 0; i < 4; i++)
            af[i] = *(const short8*)&Als[(wm * 64 + i * 16 + fr) * 32 + kb];
        #pragma unroll
        for (int j = 0; j < 4; j++)
            bfr[j] = *(const short8*)&Bls[(wn * 64 + j * 16 + fr) * 32 + kb];
        #pragma unroll
        for (int i = 0; i < 4; i++)
            #pragma unroll
            for (int j = 0; j < 4; j++)
                acc[i][j] = __builtin_amdgcn_mfma_f32_16x16x32_bf16(
                    af[i], bfr[j], acc[i][j], 0, 0, 0);
    }

    const int fr = ln & 15, rq = (ln >> 4) * 4;
    #pragma unroll
    for (int j = 0; j < 4; j++) {
        const int col = n0 + wn * 64 + j * 16 + fr;
        const float bv = bias[col];
        #pragma unroll
        for (int i = 0; i < 4; i++) {
            #pragma unroll
            for (int r = 0; r < 4; r++) {
                const int row = m0 + wm * 64 + i * 16 + rq + r;
                float v = acc[i][j][r] + bv;
                if (relu) v = fmaxf(v, 0.f);
                C[(size_t)row * N + col] = f2bf(v);
            }
        }
    }
}

// ---------------------------------------------------------------------------
// Softmax over groups of 16 (bf16 in-place)
// ---------------------------------------------------------------------------
__global__ __launch_bounds__(256) void softmax16(ushort* __restrict__ aw, int total)
{
    const int t = blockIdx.x * 256 + threadIdx.x;
    if (t >= total) return;
    ushort* p = aw + (size_t)t * 16;
    float v[16];
    #pragma unroll
    for (int i = 0; i < 16; i++) v[i] = bf2f(p[i]);
    float m = v[0];
    #pragma unroll
    for (int i = 1; i < 16; i++) m = fmaxf(m, v[i]);
    float s = 0.f;
    #pragma unroll
    for (int i = 0; i < 16; i++) { v[i] = __expf(v[i] - m); s += v[i]; }
    const float inv = 1.f / s;
    #pragma unroll
    for (int i = 0; i < 16; i++) p[i] = f2bf(v[i] * inv);
}

// ---------------------------------------------------------------------------
// Deformable sampling, bf16 value. Block = 8 queries x (8 heads x 4 chan-grps).
// Each thread owns 8 channels (one uint4 = bf16x8 per gather).
// ---------------------------------------------------------------------------
__global__ __launch_bounds__(256) void sample2(
    const ushort* __restrict__ value, const ushort* __restrict__ off,
    const ushort* __restrict__ aw, const float* __restrict__ refp,
    ushort* __restrict__ samp)
{
    const int t = threadIdx.x;
    const int q = blockIdx.x * 8 + (t >> 5);
    const int w = t & 31;
    const int h = w >> 2, cg = w & 3;
    const int b = q / S_;

    const float* rp = refp + (size_t)q * 8;
    const ushort* ofq = off + (size_t)q * 256 + h * 32;
    const ushort* awq = aw + (size_t)q * 128 + h * 16;
    const ushort* vb = value + (size_t)b * S_ * 256 + h * 32 + cg * 8;

    float acc[8] = {0.f, 0.f, 0.f, 0.f, 0.f, 0.f, 0.f, 0.f};

    #pragma unroll
    for (int l = 0; l < 4; l++) {
        const int Wl = c_lW[l], Hl = c_lH[l], st = c_lS[l];
        const float fW = (float)Wl, fH = (float)Hl;
        const float rx = rp[l * 2], ry = rp[l * 2 + 1];
        #pragma unroll
        for (int p = 0; p < 4; p++) {
            const int s = l * 4 + p;
            const float a = bf2f(awq[s]);
            const float x = (rx + bf2f(ofq[s * 2]) / fW) * fW - 0.5f;
            const float y = (ry + bf2f(ofq[s * 2 + 1]) / fH) * fH - 0.5f;
            const float fx0 = floorf(x), fy0 = floorf(y);
            const float dx = x - fx0, dy = y - fy0;
            const int x0 = (int)fx0, y0 = (int)fy0;
            const float cw0 = a * (1.f - dx) * (1.f - dy);
            const float cw1 = a * dx * (1.f - dy);
            const float cw2 = a * (1.f - dx) * dy;
            const float cw3 = a * dx * dy;
            const float cw[4] = {cw0, cw1, cw2, cw3};
            const int cx[4] = {x0, x0 + 1, x0, x0 + 1};
            const int cy[4] = {y0, y0, y0 + 1, y0 + 1};
            #pragma unroll
            for (int cn = 0; cn < 4; cn++) {
                const int xi = cx[cn], yi = cy[cn];
                const bool ok = (xi >= 0) & (xi < Wl) & (yi >= 0) & (yi < Hl);
                const float wgt = ok ? cw[cn] : 0.f;
                const int xc = min(max(xi, 0), Wl - 1);
                const int yc = min(max(yi, 0), Hl - 1);
                const uint4 v = *(const uint4*)(vb + (size_t)(st + yc * Wl + xc) * 256);
                const uint uu[4] = {v.x, v.y, v.z, v.w};
                #pragma unroll
                for (int i2 = 0; i2 < 4; i2++) {
                    acc[2 * i2]     += wgt * __uint_as_float(uu[i2] << 16);
                    acc[2 * i2 + 1] += wgt * __uint_as_float(uu[i2] & 0xffff0000u);
                }
            }
        }
    }

    uint4 o;
    o.x = (uint)f2bf(acc[0]) | ((uint)f2bf(acc[1]) << 16);
    o.y = (uint)f2bf(acc[2]) | ((uint)f2bf(acc[3]) << 16);
    o.z = (uint)f2bf(acc[4]) | ((uint)f2bf(acc[5]) << 16);
    o.w = (uint)f2bf(acc[6]) | ((uint)f2bf(acc[7]) << 16);
    *(uint4*)(samp + (size_t)q * 256 + h * 32 + cg * 8) = o;
}

// ---------------------------------------------------------------------------
// LayerNorm over D=256: v = (a32 ? a32 : bf(a16)) + bf(r16); out f32 or bf16.
// ---------------------------------------------------------------------------
__global__ __launch_bounds__(256) void ln_mix(
    const float* __restrict__ a32, const ushort* __restrict__ a16,
    const ushort* __restrict__ r16,
    const float* __restrict__ g, const float* __restrict__ be,
    float* __restrict__ o32, ushort* __restrict__ o16)
{
    const int row = blockIdx.x, t = threadIdx.x;
    const size_t base = (size_t)row * 256 + t;

    const float v = (a32 ? a32[base] : bf2f(a16[base])) + bf2f(r16[base]);

    __shared__ float red[4], red2[4];
    const int wid = t >> 6, lane = t & 63;

    float s = v;
    #pragma unroll
    for (int o = 32; o > 0; o >>= 1) s += __shfl_down(s, o);
    if (lane == 0) red[wid] = s;
    __syncthreads();
    const float mean = (red[0] + red[1] + red[2] + red[3]) * (1.f / 256.f);

    const float dv = v - mean;
    float s2 = dv * dv;
    #pragma unroll
    for (int o = 32; o > 0; o >>= 1) s2 += __shfl_down(s2, o);
    if (lane == 0) red2[wid] = s2;
    __syncthreads();
    const float var = (red2[0] + red2[1] + red2[2] + red2[3]) * (1.f / 256.f);

    const float res = dv * rsqrtf(var + EPS_) * g[t] + be[t];
    if (o32) o32[base] = res;
    else     o16[base] = f2bf(res);
}

// ---------------------------------------------------------------------------
extern "C" void kernel_launch(void* const* d_in, const int* in_sizes, int n_in,
                              void* d_out, int out_size, void* d_ws, size_t ws_size,
                              hipStream_t stream)
{
    const float* src    = (const float*)d_in[0];
    const float* pos    = (const float*)d_in[1];
    const float* refp   = (const float*)d_in[2];
    const float* W_off  = (const float*)d_in[5];
    const float* b_off  = (const float*)d_in[6];
    const float* W_attn = (const float*)d_in[7];
    const float* b_attn = (const float*)d_in[8];
    const float* W_val  = (const float*)d_in[9];
    const float* b_val  = (const float*)d_in[10];
    const float* W_out  = (const float*)d_in[11];
    const float* b_out  = (const float*)d_in[12];
    const float* g1     = (const float*)d_in[13];
    const float* be1    = (const float*)d_in[14];
    const float* W_ff1  = (const float*)d_in[15];
    const float* b_ff1  = (const float*)d_in[16];
    const float* W_ff2  = (const float*)d_in[17];
    const float* b_ff2  = (const float*)d_in[18];
    const float* g2     = (const float*)d_in[19];
    const float* be2    = (const float*)d_in[20];
    float* out = (float*)d_out;

    const size_t szMDh = (size_t)M_ * 256 * 2;   // 22,282,240 B
    const size_t szAWh = (size_t)M_ * 128 * 2;   // 11,141,120 B

    char* ws = (char*)d_ws;
    // weight region (bf16, transposed [N][K])
    ushort* WT_val  = (ushort*)(ws + 0);
    ushort* WT_off  = (ushort*)(ws + 131072);
    ushort* WT_attn = (ushort*)(ws + 262144);
    ushort* WT_out  = (ushort*)(ws + 327680);
    ushort* WT_ff1  = (ushort*)(ws + 458752);
    ushort* WT_ff2  = (ushort*)(ws + 983040);

    const size_t o_src = 2097152;            // src_bf  -> later samp
    const size_t o_q   = o_src + szMDh;      // q_bf    -> later attn_bf
    const size_t o_val = o_q   + szMDh;      // value_bf
    const size_t o_off = o_val + szMDh;      // off_bf
    const size_t o_aw  = o_off + szMDh;      // aw_bf
    const size_t o_x   = o_aw  + szAWh;      // x_bf
    const size_t o_ffn = o_x   + szMDh;      // ffn_bf
    // total = 2MB + 6*szMDh + szAWh = 146.9 MB (< proven-available ~157MB)

    ushort* src_bf = (ushort*)(ws + o_src);
    ushort* q_bf   = (ushort*)(ws + o_q);
    ushort* val_bf = (ushort*)(ws + o_val);
    ushort* off_bf = (ushort*)(ws + o_off);
    ushort* aw_bf  = (ushort*)(ws + o_aw);
    ushort* x_bf   = (ushort*)(ws + o_x);
    ushort* ffn_bf = (ushort*)(ws + o_ffn);
    ushort* samp_bf = src_bf;   // src_bf dead after value GEMM
    ushort* attn_bf = q_bf;     // q_bf dead after off/attn GEMMs
    ushort* hbuf    = src_bf;   // spans src..off regions = 4*szMDh = exactly M*1024*2

    // 0) weight transpose+convert (tiny)
    wconv<<<(256 * 256 + 255) / 256, 256, 0, stream>>>(W_val, WT_val, 256, 256);
    wconv<<<(256 * 256 + 255) / 256, 256, 0, stream>>>(W_off, WT_off, 256, 256);
    wconv<<<(256 * 128 + 255) / 256, 256, 0, stream>>>(W_attn, WT_attn, 256, 128);
    wconv<<<(256 * 256 + 255) / 256, 256, 0, stream>>>(W_out, WT_out, 256, 256);
    wconv<<<(256 * 1024 + 255) / 256, 256, 0, stream>>>(W_ff1, WT_ff1, 256, 1024);
    wconv<<<(1024 * 256 + 255) / 256, 256, 0, stream>>>(W_ff2, WT_ff2, 1024, 256);

    // 1) activation converts
    cvt_pair<<<(M_ * 256 / 4 + 255) / 256, 256, 0, stream>>>(src, pos, src_bf, q_bf);

    // 2) value = src @ W_val + b_val
    mgemm<<<dim3(2, M_ / 128), 256, 0, stream>>>(src_bf, WT_val, b_val, val_bf, M_, 256, 256, 0);
    // 3) off = (src+pos) @ W_off + b_off
    mgemm<<<dim3(2, M_ / 128), 256, 0, stream>>>(q_bf, WT_off, b_off, off_bf, M_, 256, 256, 0);
    // 4) aw = (src+pos) @ W_attn + b_attn
    mgemm<<<dim3(1, M_ / 128), 256, 0, stream>>>(q_bf, WT_attn, b_attn, aw_bf, M_, 128, 256, 0);
    // 5) softmax over 16
    softmax16<<<(M_ * 8 + 255) / 256, 256, 0, stream>>>(aw_bf, M_ * 8);
    // 6) sampling
    sample2<<<M_ / 8, 256, 0, stream>>>(val_bf, off_bf, aw_bf, refp, samp_bf);
    // 7) attn_out = samp @ W_out + b_out
    mgemm<<<dim3(2, M_ / 128), 256, 0, stream>>>(samp_bf, WT_out, b_out, attn_bf, M_, 256, 256, 0);
    // 8) x = LN(src + attn)
    ln_mix<<<M_, 256, 0, stream>>>(src, nullptr, attn_bf, g1, be1, nullptr, x_bf);
    // 9) FFN1: h = relu(x @ W_ff1 + b_ff1)
    mgemm<<<dim3(8, M_ / 128), 256, 0, stream>>>(x_bf, WT_ff1, b_ff1, hbuf, M_, DFF_, 256, 1);
    // 10) FFN2: ffn = h @ W_ff2 + b_ff2
    mgemm<<<dim3(2, M_ / 128), 256, 0, stream>>>(hbuf, WT_ff2, b_ff2, ffn_bf, M_, 256, DFF_, 0);
    // 11) out = LN(x + ffn)
    ln_mix<<<M_, 256, 0, stream>>>(nullptr, x_bf, ffn_bf, g2, be2, out, nullptr);
}